// Round 1
// baseline (151.551 us; speedup 1.0000x reference)
//
#include <hip/hip_runtime.h>

#define NUM_CLASSES 5
#define BATCH 4
#define NPB (64 * 256 * 256)            // voxels per batch = 4,194,304
#define VEC_PER_BATCH (NPB / 4)         // int4 vectors per batch = 1,048,576
#define THREADS 512                     // 8 waves/block
#define VECS 8                          // int4 per thread per input (32 voxels)
#define CHUNK 4                         // int4 per forced load burst (16 voxels)
#define BLOCKS_X (VEC_PER_BATCH / (THREADS * VECS))   // 256 per batch (unchanged)
#define SLOTS 15                        // 5 pred, 5 targ, 5 inter
#define PSTRIDE 16                      // padded per-block partial stride

// d_ws: partial[block][PSTRIDE] uints, block = b*BLOCKS_X + bx. Same 64 KB
// footprint/layout as before. No zero-init needed: every slot dice_final_kernel
// reads is written unconditionally.
//
// Round theory: grid was 1024 blocks x 4 waves = 16 waves/CU (launch_bounds
// min-waves/EU = 4) -> latency-bound at 3.0 TB/s effective. This version keeps
// the grid at 1024 blocks but doubles the block to 512 threads with
// __launch_bounds__(512, 8) -> 32 waves/CU. Per-thread work halves (VECS 8),
// burst halves (CHUNK 4 -> 8x int4 = 32 data VGPRs in flight) so the kernel
// fits the 64-VGPR budget that 8 waves/SIMD requires.

__global__ __launch_bounds__(THREADS, 8) void dice_count_kernel(
    const int* __restrict__ pred, const int* __restrict__ targ,
    unsigned int* __restrict__ partial) {
  const int b = blockIdx.y;
  const int4* __restrict__ p4 = (const int4*)(pred + (long long)b * NPB);
  const int4* __restrict__ t4 = (const int4*)(targ + (long long)b * NPB);

  const int base = blockIdx.x * (THREADS * VECS) + threadIdx.x;

  // Packed per-lane counters: class c in bits [6c, 6c+6); per-chunk count <= 16.
  unsigned accP[2] = {0, 0}, accT[2] = {0, 0}, accI[2] = {0, 0};

#pragma unroll
  for (int h = 0; h < 2; ++h) {
    int4 pv[CHUNK], tv[CHUNK];
    // Burst: 8 independent 16B loads (32 data VGPRs live). sched_barrier(0)
    // keeps the scheduler from sinking these into their uses.
#pragma unroll
    for (int k = 0; k < CHUNK; ++k) {
      const int idx = base + (h * CHUNK + k) * THREADS;
      pv[k] = p4[idx];
      tv[k] = t4[idx];
    }
    __builtin_amdgcn_sched_barrier(0);
    unsigned aP = 0, aT = 0, aI = 0;
#define ACC_ELEM(PE, TE)                               \
    {                                                  \
      const unsigned op = 1u << (6u * (unsigned)(PE)); \
      aP += op;                                        \
      aT += 1u << (6u * (unsigned)(TE));               \
      aI += ((PE) == (TE)) ? op : 0u;                  \
    }
#pragma unroll
    for (int k = 0; k < CHUNK; ++k) {
      ACC_ELEM(pv[k].x, tv[k].x)
      ACC_ELEM(pv[k].y, tv[k].y)
      ACC_ELEM(pv[k].z, tv[k].z)
      ACC_ELEM(pv[k].w, tv[k].w)
    }
    accP[h] = aP; accT[h] = aT; accI[h] = aI;
  }

  // Unpack 6-bit fields of both chunks -> 16-bit pairs (per-field <= 32, fits).
#define UNPACK(A, R01, R23, R4)                                          \
  unsigned R01 = ((A[0] & 63u) + (A[1] & 63u)) |                         \
                 ((((A[0] >> 6) & 63u) + ((A[1] >> 6) & 63u)) << 16);    \
  unsigned R23 = (((A[0] >> 12) & 63u) + ((A[1] >> 12) & 63u)) |         \
                 ((((A[0] >> 18) & 63u) + ((A[1] >> 18) & 63u)) << 16);  \
  unsigned R4 = ((A[0] >> 24) & 63u) + ((A[1] >> 24) & 63u);
  UNPACK(accP, p01, p23, p4r)
  UNPACK(accT, t01, t23, t4r)
  UNPACK(accI, i01, i23, i4r)

  // 64-lane butterfly; 16-bit fields hold <= 64*32 = 2048, no overflow.
#pragma unroll
  for (int off = 32; off >= 1; off >>= 1) {
    p01 += (unsigned)__shfl_xor((int)p01, off);
    p23 += (unsigned)__shfl_xor((int)p23, off);
    p4r += (unsigned)__shfl_xor((int)p4r, off);
    t01 += (unsigned)__shfl_xor((int)t01, off);
    t23 += (unsigned)__shfl_xor((int)t23, off);
    t4r += (unsigned)__shfl_xor((int)t4r, off);
    i01 += (unsigned)__shfl_xor((int)i01, off);
    i23 += (unsigned)__shfl_xor((int)i23, off);
    i4r += (unsigned)__shfl_xor((int)i4r, off);
  }

  __shared__ unsigned int s[SLOTS];
  if (threadIdx.x < SLOTS) s[threadIdx.x] = 0;
  __syncthreads();

  if ((threadIdx.x & 63) == 0) {
    atomicAdd(&s[0], p01 & 0xFFFFu);
    atomicAdd(&s[1], p01 >> 16);
    atomicAdd(&s[2], p23 & 0xFFFFu);
    atomicAdd(&s[3], p23 >> 16);
    atomicAdd(&s[4], p4r);
    atomicAdd(&s[5], t01 & 0xFFFFu);
    atomicAdd(&s[6], t01 >> 16);
    atomicAdd(&s[7], t23 & 0xFFFFu);
    atomicAdd(&s[8], t23 >> 16);
    atomicAdd(&s[9], t4r);
    atomicAdd(&s[10], i01 & 0xFFFFu);
    atomicAdd(&s[11], i01 >> 16);
    atomicAdd(&s[12], i23 & 0xFFFFu);
    atomicAdd(&s[13], i23 >> 16);
    atomicAdd(&s[14], i4r);
  }
  __syncthreads();

  if (threadIdx.x < SLOTS)
    partial[(b * BLOCKS_X + blockIdx.x) * PSTRIDE + threadIdx.x] = s[threadIdx.x];
}

__global__ __launch_bounds__(256) void dice_final_kernel(
    const unsigned int* __restrict__ partial, float* __restrict__ out) {
  // 240 active threads: t = (bb*SLOTS + slot)*4 + q; q splits the 256 blocks
  // of one batch into quarters for parallel latency hiding.
  __shared__ unsigned int red[BATCH * SLOTS][4];
  const int t = threadIdx.x;
  if (t < BATCH * SLOTS * 4) {
    const int q = t & 3;
    const int s = (t >> 2) % SLOTS;
    const int bb = (t >> 2) / SLOTS;
    unsigned int sum = 0;
    for (int j = q * (BLOCKS_X / 4); j < (q + 1) * (BLOCKS_X / 4); ++j)
      sum += partial[(bb * BLOCKS_X + j) * PSTRIDE + s];
    red[(t >> 2)][q] = sum;
  }
  __syncthreads();
  if (t < NUM_CLASSES) {
    float acc = 0.0f;
#pragma unroll
    for (int bb = 0; bb < BATCH; ++bb) {
      const int ip = bb * SLOTS + t;
      const int it = bb * SLOTS + 5 + t;
      const int ii = bb * SLOTS + 10 + t;
      const float ps = (float)(red[ip][0] + red[ip][1] + red[ip][2] + red[ip][3]);
      const float ts = (float)(red[it][0] + red[it][1] + red[it][2] + red[it][3]);
      const float is = (float)(red[ii][0] + red[ii][1] + red[ii][2] + red[ii][3]);
      float num = 2.0f * is;
      float den = ps + ts;
      if (den == 0.0f) { num = 1.0f; den = 1.0f; }
      acc += num / den;
    }
    out[t] = acc * (1.0f / BATCH);
  }
}

extern "C" void kernel_launch(void* const* d_in, const int* in_sizes, int n_in,
                              void* d_out, int out_size, void* d_ws, size_t ws_size,
                              hipStream_t stream) {
  const int* pred = (const int*)d_in[0];
  const int* targ = (const int*)d_in[1];
  float* out = (float*)d_out;
  unsigned int* partial = (unsigned int*)d_ws;

  dim3 grid(BLOCKS_X, BATCH);
  dice_count_kernel<<<grid, THREADS, 0, stream>>>(pred, targ, partial);
  dice_final_kernel<<<1, 256, 0, stream>>>(partial, out);
}

// Round 2
// 147.378 us; speedup vs baseline: 1.0283x; 1.0283x over previous
//
#include <hip/hip_runtime.h>

#define NUM_CLASSES 5
#define BATCH 4
#define NPB (64 * 256 * 256)            // voxels per batch = 4,194,304
#define VEC_PER_BATCH (NPB / 4)         // int4 vectors per batch = 1,048,576
#define THREADS 256
#define VECS 16                         // int4 per thread per input (64 voxels)
#define CHUNKV 4                        // int4 per buffer fill (16 voxels)
#define BLOCKS_X (VEC_PER_BATCH / (THREADS * VECS))   // 256 per batch
#define SLOTS 15                        // 5 pred, 5 targ, 5 inter
#define PSTRIDE 16                      // padded per-block partial stride

// d_ws: partial[block][PSTRIDE] uints, block = b*BLOCKS_X + bx. Layout identical
// to previous rounds (64 KB). No zero-init needed.
//
// Round-2 theory: rounds 0/1 were MLP-starved, not wave-starved (occupancy
// 34->52% moved BW 0%). VGPR_Count=32/40 proves RA recycled the "burst"
// registers -> <1 load in flight per wave. This version double-buffers two
// named-register sets of 8 int4 each (A/B) and consumes in issue order, so
// the steady state always has 8 loads outstanding while 8 more are consumed
// (compiler emits partial vmcnt waits). __launch_bounds__(256,4) raises the
// VGPR cap to 128 so the ~80 live registers actually stay in registers.

__global__ __launch_bounds__(THREADS, 4) void dice_count_kernel(
    const int* __restrict__ pred, const int* __restrict__ targ,
    unsigned int* __restrict__ partial) {
  const int b = blockIdx.y;
  const int4* __restrict__ p4 = (const int4*)(pred + (long long)b * NPB);
  const int4* __restrict__ t4 = (const int4*)(targ + (long long)b * NPB);

  const int base = blockIdx.x * (THREADS * VECS) + threadIdx.x;

  // Packed per-lane counters: class c in bits [6c, 6c+6).
  // acc*0 accumulates chunks 0-1 (32 voxels <= 63 per class), acc*1 chunks 2-3.
  unsigned accP0 = 0, accP1 = 0, accT0 = 0, accT1 = 0, accI0 = 0, accI1 = 0;

  // Two named-register buffers, 8 int4 each. Named scalars (not arrays) so
  // every access is compile-time static -> guaranteed register residency.
  int4 pa0, pa1, pa2, pa3, ta0, ta1, ta2, ta3;
  int4 pb0, pb1, pb2, pb3, tb0, tb1, tb2, tb3;

#define IDX(KK, CC) (base + ((KK) * CHUNKV + (CC)) * THREADS)
#define LOAD_A(KK)                                                   \
  pa0 = p4[IDX(KK, 0)]; pa1 = p4[IDX(KK, 1)];                        \
  pa2 = p4[IDX(KK, 2)]; pa3 = p4[IDX(KK, 3)];                        \
  ta0 = t4[IDX(KK, 0)]; ta1 = t4[IDX(KK, 1)];                        \
  ta2 = t4[IDX(KK, 2)]; ta3 = t4[IDX(KK, 3)];
#define LOAD_B(KK)                                                   \
  pb0 = p4[IDX(KK, 0)]; pb1 = p4[IDX(KK, 1)];                        \
  pb2 = p4[IDX(KK, 2)]; pb3 = p4[IDX(KK, 3)];                        \
  tb0 = t4[IDX(KK, 0)]; tb1 = t4[IDX(KK, 1)];                        \
  tb2 = t4[IDX(KK, 2)]; tb3 = t4[IDX(KK, 3)];

#define ACC_ELEM(PE, TE, AP, AT, AI)                   \
    {                                                  \
      const unsigned op = 1u << (6u * (unsigned)(PE)); \
      AP += op;                                        \
      AT += 1u << (6u * (unsigned)(TE));               \
      AI += ((PE) == (TE)) ? op : 0u;                  \
    }
#define CONS1(PV, TV, AP, AT, AI)                      \
    ACC_ELEM(PV.x, TV.x, AP, AT, AI)                   \
    ACC_ELEM(PV.y, TV.y, AP, AT, AI)                   \
    ACC_ELEM(PV.z, TV.z, AP, AT, AI)                   \
    ACC_ELEM(PV.w, TV.w, AP, AT, AI)
#define CONSUME_A(AP, AT, AI)                          \
    CONS1(pa0, ta0, AP, AT, AI) CONS1(pa1, ta1, AP, AT, AI) \
    CONS1(pa2, ta2, AP, AT, AI) CONS1(pa3, ta3, AP, AT, AI)
#define CONSUME_B(AP, AT, AI)                          \
    CONS1(pb0, tb0, AP, AT, AI) CONS1(pb1, tb1, AP, AT, AI) \
    CONS1(pb2, tb2, AP, AT, AI) CONS1(pb3, tb3, AP, AT, AI)

  // Software pipeline: next buffer's 8 loads are issued before the current
  // buffer is consumed; sched_barrier(0) pins that order so the consume's
  // vmcnt wait leaves the just-issued loads in flight.
  LOAD_A(0)
  LOAD_B(1)
  __builtin_amdgcn_sched_barrier(0);
  CONSUME_A(accP0, accT0, accI0)
  LOAD_A(2)
  __builtin_amdgcn_sched_barrier(0);
  CONSUME_B(accP0, accT0, accI0)
  LOAD_B(3)
  __builtin_amdgcn_sched_barrier(0);
  CONSUME_A(accP1, accT1, accI1)
  CONSUME_B(accP1, accT1, accI1)

  // Unpack 6-bit fields of both halves -> 16-bit pairs (per-field <= 32+32=64).
#define UNPACK(A0, A1, R01, R23, R4)                                     \
  unsigned R01 = ((A0 & 63u) + (A1 & 63u)) |                             \
                 ((((A0 >> 6) & 63u) + ((A1 >> 6) & 63u)) << 16);        \
  unsigned R23 = (((A0 >> 12) & 63u) + ((A1 >> 12) & 63u)) |             \
                 ((((A0 >> 18) & 63u) + ((A1 >> 18) & 63u)) << 16);      \
  unsigned R4 = ((A0 >> 24) & 63u) + ((A1 >> 24) & 63u);
  UNPACK(accP0, accP1, p01, p23, p4r)
  UNPACK(accT0, accT1, t01, t23, t4r)
  UNPACK(accI0, accI1, i01, i23, i4r)

  // 64-lane butterfly; 16-bit fields hold <= 64*64 = 4096, no overflow.
#pragma unroll
  for (int off = 32; off >= 1; off >>= 1) {
    p01 += (unsigned)__shfl_xor((int)p01, off);
    p23 += (unsigned)__shfl_xor((int)p23, off);
    p4r += (unsigned)__shfl_xor((int)p4r, off);
    t01 += (unsigned)__shfl_xor((int)t01, off);
    t23 += (unsigned)__shfl_xor((int)t23, off);
    t4r += (unsigned)__shfl_xor((int)t4r, off);
    i01 += (unsigned)__shfl_xor((int)i01, off);
    i23 += (unsigned)__shfl_xor((int)i23, off);
    i4r += (unsigned)__shfl_xor((int)i4r, off);
  }

  __shared__ unsigned int s[SLOTS];
  if (threadIdx.x < SLOTS) s[threadIdx.x] = 0;
  __syncthreads();

  if ((threadIdx.x & 63) == 0) {
    atomicAdd(&s[0], p01 & 0xFFFFu);
    atomicAdd(&s[1], p01 >> 16);
    atomicAdd(&s[2], p23 & 0xFFFFu);
    atomicAdd(&s[3], p23 >> 16);
    atomicAdd(&s[4], p4r);
    atomicAdd(&s[5], t01 & 0xFFFFu);
    atomicAdd(&s[6], t01 >> 16);
    atomicAdd(&s[7], t23 & 0xFFFFu);
    atomicAdd(&s[8], t23 >> 16);
    atomicAdd(&s[9], t4r);
    atomicAdd(&s[10], i01 & 0xFFFFu);
    atomicAdd(&s[11], i01 >> 16);
    atomicAdd(&s[12], i23 & 0xFFFFu);
    atomicAdd(&s[13], i23 >> 16);
    atomicAdd(&s[14], i4r);
  }
  __syncthreads();

  if (threadIdx.x < SLOTS)
    partial[(b * BLOCKS_X + blockIdx.x) * PSTRIDE + threadIdx.x] = s[threadIdx.x];
}

__global__ __launch_bounds__(256) void dice_final_kernel(
    const unsigned int* __restrict__ partial, float* __restrict__ out) {
  // 240 active threads: t = (bb*SLOTS + slot)*4 + q; q splits the 256 blocks
  // of one batch into quarters for parallel latency hiding.
  __shared__ unsigned int red[BATCH * SLOTS][4];
  const int t = threadIdx.x;
  if (t < BATCH * SLOTS * 4) {
    const int q = t & 3;
    const int s = (t >> 2) % SLOTS;
    const int bb = (t >> 2) / SLOTS;
    unsigned int sum = 0;
    for (int j = q * (BLOCKS_X / 4); j < (q + 1) * (BLOCKS_X / 4); ++j)
      sum += partial[(bb * BLOCKS_X + j) * PSTRIDE + s];
    red[(t >> 2)][q] = sum;
  }
  __syncthreads();
  if (t < NUM_CLASSES) {
    float acc = 0.0f;
#pragma unroll
    for (int bb = 0; bb < BATCH; ++bb) {
      const int ip = bb * SLOTS + t;
      const int it = bb * SLOTS + 5 + t;
      const int ii = bb * SLOTS + 10 + t;
      const float ps = (float)(red[ip][0] + red[ip][1] + red[ip][2] + red[ip][3]);
      const float ts = (float)(red[it][0] + red[it][1] + red[it][2] + red[it][3]);
      const float is = (float)(red[ii][0] + red[ii][1] + red[ii][2] + red[ii][3]);
      float num = 2.0f * is;
      float den = ps + ts;
      if (den == 0.0f) { num = 1.0f; den = 1.0f; }
      acc += num / den;
    }
    out[t] = acc * (1.0f / BATCH);
  }
}

extern "C" void kernel_launch(void* const* d_in, const int* in_sizes, int n_in,
                              void* d_out, int out_size, void* d_ws, size_t ws_size,
                              hipStream_t stream) {
  const int* pred = (const int*)d_in[0];
  const int* targ = (const int*)d_in[1];
  float* out = (float*)d_out;
  unsigned int* partial = (unsigned int*)d_ws;

  dim3 grid(BLOCKS_X, BATCH);
  dice_count_kernel<<<grid, THREADS, 0, stream>>>(pred, targ, partial);
  dice_final_kernel<<<1, 256, 0, stream>>>(partial, out);
}